// Round 4
// baseline (575.276 us; speedup 1.0000x reference)
//
#include <hip/hip_runtime.h>
#include <hip/hip_bf16.h>

// Problem constants (from reference): B=32, N=8192, C=512, K=128
#define PB 32
#define PN 8192
#define PC 512
#define PK 128

// Dtype model (explains R0-R3 failures EXACTLY):
//   one_hot : float32, B*N*C elements (512 MB)
//   id      : int32, 1 element
//   d_out   : float32, B*N (block_id) ++ B*K (indices) = 266240 floats
// Harness compares vs a bf16-rounded np reference (threshold 0.02*8192=163.84).
// R1/R2: bf16 writes into float chunk0 -> 0x45FFxxxx = 8160.  R3: one_hot read
// as bf16 -> wrong-column 0/1s (passed threshold) -> compact starved -> 8192.

// Kernel A: gather column `id` from one_hot (f32), write float32 output 0.
__global__ __launch_bounds__(256) void gather_col(
    const float* __restrict__ one_hot,
    const int* __restrict__ id_ptr,
    float* __restrict__ out0)
{
    int i = blockIdx.x * 256 + threadIdx.x;      // 0 .. B*N-1
    int id = id_ptr[0];
    out0[i] = one_hot[(size_t)i * PC + (size_t)id];
}

// Kernel B: per-batch stable compaction of positions where col != 0.
// One block per batch, 1024 threads, 8 phases of 1024 positions each.
// Ascending n == stable argsort of the 0/1 key, first K (exactly K ones/row).
__global__ __launch_bounds__(1024) void compact_idx(
    const float* __restrict__ out0,
    float* __restrict__ out1)                    // indices as float32
{
    const int b    = blockIdx.x;
    const int tid  = threadIdx.x;
    const int wave = tid >> 6;
    const int lane = tid & 63;

    __shared__ unsigned int wave_cnt[16];

    const float* row = out0 + (size_t)b * PN;

    // Prefetch all 8 values (independent coalesced loads, all in flight).
    float vals[8];
#pragma unroll
    for (int p = 0; p < 8; ++p)
        vals[p] = row[p * 1024 + tid];

    unsigned int running = 0;  // global running count of ones so far
#pragma unroll
    for (int p = 0; p < 8; ++p) {
        const bool pred = (vals[p] != 0.0f);
        const unsigned long long mask = __ballot(pred);
        if (lane == 0) wave_cnt[wave] = (unsigned int)__popcll(mask);
        __syncthreads();

        // 16-wave scan: every thread reads all counts (LDS broadcast reads).
        unsigned int prefix = 0, total = 0;
#pragma unroll
        for (int w = 0; w < 16; ++w) {
            unsigned int c = wave_cnt[w];
            total += c;
            if (w < wave) prefix += c;
        }

        if (pred) {
            unsigned int rank = (unsigned int)__popcll(mask & ((1ULL << lane) - 1ULL));
            unsigned int pos  = running + prefix + rank;
            if (pos < PK) {
                out1[b * PK + pos] = (float)(p * 1024 + tid);
            }
        }
        running += total;
        __syncthreads();  // protect wave_cnt before next phase overwrites it
    }
}

extern "C" void kernel_launch(void* const* d_in, const int* in_sizes, int n_in,
                              void* d_out, int out_size, void* d_ws, size_t ws_size,
                              hipStream_t stream) {
    // Resolve inputs by size: the 1-element input is `id`, the big one is one_hot.
    const float* one_hot = nullptr;
    const int* id_ptr = nullptr;
    for (int i = 0; i < n_in; ++i) {
        if (in_sizes[i] == 1) id_ptr = (const int*)d_in[i];
        else                  one_hot = (const float*)d_in[i];
    }

    float* out0 = (float*)d_out;                    // B*N floats
    float* out1 = (float*)d_out + (size_t)PB * PN;  // B*K floats

    gather_col<<<dim3((PB * PN) / 256), dim3(256), 0, stream>>>(one_hot, id_ptr, out0);
    compact_idx<<<dim3(PB), dim3(1024), 0, stream>>>(out0, out1);
}